// Round 13
// baseline (53.457 us; speedup 1.0000x reference)
//
#include <hip/hip_runtime.h>

// R13 = R12 exactly, with gemm_kernel launched TWICE (idempotent) to measure
// gemm's true cost as dur(R13) - dur(R12). No other changes.
//
// Indexed segmented linear, bucketed-by-element grouped GEMM with bf16 MFMA.
//   segments (mi, mo, d): (96,96,1), (64,64,3), (32,32,5)
//   y[b, o*d+m] = sum_i x[b, i*d+m] * W[idx[b], i*mo+o]

#define BATCH     16384
#define IN_SIZE   448
#define OUT_SIZE  448
#define W_SIZE    14336
#define NELEM     64
#define RTILE     32
#define MAXTILES  576         // >= 512 + 63 worst case
#define WT_ELEM   15872       // halves: 96*104 + 64*72 + 32*40

typedef __attribute__((ext_vector_type(8))) short short8;
typedef __attribute__((ext_vector_type(8))) unsigned short us8;
typedef __attribute__((ext_vector_type(4))) float f32x4;

__device__ __forceinline__ unsigned short f2bf(float f) {
    unsigned int u = __float_as_uint(f);
    u += 0x7fffu + ((u >> 16) & 1u);        // round-to-nearest-even
    return (unsigned short)(u >> 16);
}

// ---------------- K1: hist (blk 0-63) + wprep (blk 64-127) ----------------

__device__ __forceinline__ void wprep_seg(const float* __restrict__ we,
                                          unsigned short* __restrict__ de,
                                          unsigned short* lw, int t,
                                          int SRC, int CNT, int MO, int STR,
                                          int DB, int LWS, int MI) {
    for (int g = t; g < CNT; g += 256) {
        const int i = g / MO, o = g - i * MO;
        lw[i * LWS + o] = f2bf(we[SRC + g]);
    }
    __syncthreads();
    const int TOT = MO * STR;
    for (int d = t; d < TOT; d += 256) {
        const int o = d / STR, i = d - o * STR;
        de[DB + d] = (i < MI) ? lw[i * LWS + o] : (unsigned short)0;
    }
    __syncthreads();
}

__global__ __launch_bounds__(256) void combo1_kernel(
    const int* __restrict__ widx, const float* __restrict__ weights,
    int* __restrict__ hists, unsigned short* __restrict__ wt) {
    __shared__ int h[NELEM];
    __shared__ __align__(16) unsigned short lw[9408];   // 96*98 padded
    const int t = threadIdx.x;
    if (blockIdx.x < 64) {
        if (t < NELEM) h[t] = 0;
        __syncthreads();
        atomicAdd(&h[widx[blockIdx.x * 256 + t]], 1);
        __syncthreads();
        if (t < NELEM) hists[blockIdx.x * NELEM + t] = h[t];
    } else {
        const int e = blockIdx.x - 64;
        const float* __restrict__ we = weights + e * W_SIZE;
        unsigned short* __restrict__ de = wt + (size_t)e * WT_ELEM;
        wprep_seg(we, de, lw, t,     0, 9216, 96, 104,     0, 98, 96);
        wprep_seg(we, de, lw, t,  9216, 4096, 64,  72,  9984, 66, 64);
        wprep_seg(we, de, lw, t, 13312, 1024, 32,  40, 14592, 34, 32);
    }
}

// ---------------- K2: fused scan + scatter (rowids + tables) ----------------

__global__ __launch_bounds__(256) void scatter_kernel(
    const int* __restrict__ widx, const int* __restrict__ hists,
    int* __restrict__ offsets, int* __restrict__ tileoff, int* __restrict__ blk2e,
    int* __restrict__ rowids) {
    __shared__ int tot_s[NELEM], pre_s[NELEM], base_s[NELEM];
    __shared__ int off_s[NELEM + 1], tl_s[NELEM + 1];
    const int b = blockIdx.x, t = threadIdx.x;

    if (t < NELEM) {
        int before = 0, tot = 0;
        for (int c = 0; c < 64; ++c) {
            const int h = hists[c * NELEM + t];
            before += (c < b) ? h : 0;
            tot += h;
        }
        tot_s[t] = tot; pre_s[t] = before;
    }
    __syncthreads();
    if (t == 0) {
        int o = 0, tl = 0;
        for (int e = 0; e < NELEM; ++e) {
            off_s[e] = o; tl_s[e] = tl;
            o += tot_s[e]; tl += (tot_s[e] + RTILE - 1) >> 5;
        }
        off_s[NELEM] = o; tl_s[NELEM] = tl;
    }
    __syncthreads();
    if (t < NELEM) base_s[t] = off_s[t] + pre_s[t];

    if (b == 0) {
        if (t < NELEM) { offsets[t] = off_s[t]; tileoff[t] = tl_s[t]; }
        if (t == 0)    { offsets[NELEM] = off_s[NELEM]; tileoff[NELEM] = tl_s[NELEM]; }
        for (int i = t; i < MAXTILES; i += 256) blk2e[i] = -1;
        __syncthreads();
        if (t < NELEM)
            for (int bb = tl_s[t]; bb < tl_s[t + 1]; ++bb) blk2e[bb] = t;
    }
    __syncthreads();

    const int row = b * 256 + t;
    const int e = widx[row];
    const int pos = atomicAdd(&base_s[e], 1);
    rowids[pos] = row;
}

// ---------------- K3: grouped GEMM: packed staging + transpose epilogue ------

template <int MI, int MO, int D, int XOFF, int YOFF, int WB>
__device__ __forceinline__ void do_seg(const float* __restrict__ x,
                                       const unsigned short* __restrict__ wt_e,
                                       const int* rid_s, int nrows,
                                       float* __restrict__ out,
                                       unsigned short* lds_w, unsigned short* lds_x,
                                       int t) {
    constexpr int XP   = MI * D + 8;         // x row stride (halves)
    constexpr int WSTR = MI + 8;             // W row stride (halves)
    constexpr int NT   = MO / 16;
    constexpr int KB   = MI / 32;
    constexpr int MTL  = 2 * D;
    constexpr int WCH  = (MO * WSTR) / 8;    // 16B chunks of W seg
    constexpr int FPT  = (MI * D) / 8;       // floats per thread (8 thr/row)
    constexpr int NQ   = FPT / 4;            // float4 loads per thread
    constexpr int MOD  = MO * D;             // out floats per row in this seg
    constexpr int NTW  = (MTL * NT) / 4;     // C-tiles per wave (3/6/5)
    constexpr int F4R  = MOD / 4;            // float4 per out row (24/48/40)

    const int r = t >> 3, j = t & 7;         // 8 threads per row

    // issue all gather loads first (register clause; overlaps W staging)
    const float4* __restrict__ src =
        (const float4*)(x + (size_t)rid_s[r] * IN_SIZE + XOFF + j * FPT);
    float vv[FPT];
    #pragma unroll
    for (int q = 0; q < NQ; ++q) {
        const float4 v = src[q];
        vv[q * 4 + 0] = v.x; vv[q * 4 + 1] = v.y;
        vv[q * 4 + 2] = v.z; vv[q * 4 + 3] = v.w;
    }

    // stage W segment (bf16, pre-transposed, padded): linear uint4 copies (L2)
    const uint4* __restrict__ wsrc = (const uint4*)(wt_e + WB);
    for (int idx = t; idx < WCH; idx += 256) ((uint4*)lds_w)[idx] = wsrc[idx];

    // packed de-interleave writes (compile-time folded addresses)
    if (D == 1) {
        #pragma unroll
        for (int q = 0; q < NQ; ++q) {
            ushort4 w = { f2bf(vv[q * 4 + 0]), f2bf(vv[q * 4 + 1]),
                          f2bf(vv[q * 4 + 2]), f2bf(vv[q * 4 + 3]) };
            *(ushort4*)&lds_x[r * XP + j * FPT + q * 4] = w;
        }
    } else if (D == 3) {
        #pragma unroll
        for (int m = 0; m < 3; ++m) {        // i = j*8 + b, src lc = 3b + m
            us8 w;
            #pragma unroll
            for (int bq = 0; bq < 8; ++bq) w[bq] = f2bf(vv[3 * bq + m]);
            *(us8*)&lds_x[r * XP + m * MI + j * 8] = w;
        }
    } else {                                 // D == 5: i = j*4 + b, lc = 5b + m
        #pragma unroll
        for (int m = 0; m < 5; ++m) {
            ushort4 w = { f2bf(vv[m]), f2bf(vv[5 + m]),
                          f2bf(vv[10 + m]), f2bf(vv[15 + m]) };
            *(ushort4*)&lds_x[r * XP + m * MI + j * 4] = w;
        }
    }
    __syncthreads();

    // compute: C-tiles round-robin over 4 waves, results kept in registers
    const int lane = t & 63, w = t >> 6;
    const int row_l = lane & 15, kg = lane >> 4;
    f32x4 accs[NTW];
    #pragma unroll
    for (int q = 0; q < NTW; ++q) {
        const int ct = w + q * 4;
        const int mIdx = ct / NT, nt = ct - mIdx * NT;
        const int mt = mIdx & 1, mch = mIdx >> 1;
        f32x4 acc = {0.f, 0.f, 0.f, 0.f};
        #pragma unroll
        for (int kb = 0; kb < KB; ++kb) {
            const short8 a = *(const short8*)&lds_x[(mt * 16 + row_l) * XP + mch * MI + kb * 32 + kg * 8];
            const short8 b = *(const short8*)&lds_w[(nt * 16 + row_l) * WSTR + kb * 32 + kg * 8];
            acc = __builtin_amdgcn_mfma_f32_16x16x32_bf16(a, b, acc, 0, 0, 0);
        }
        accs[q] = acc;
    }
    __syncthreads();                         // all waves done reading lds_x/lds_w

    // transpose epilogue: acc -> LDS (f32 image of the 32xMOD out tile)
    float* __restrict__ lout = (float*)lds_w;        // lds_w is the LDS base
    #pragma unroll
    for (int q = 0; q < NTW; ++q) {
        const int ct = w + q * 4;
        const int mIdx = ct / NT, nt = ct - mIdx * NT;
        const int mt = mIdx & 1, mch = mIdx >> 1;
        const int o = nt * 16 + row_l;
        #pragma unroll
        for (int jj = 0; jj < 4; ++jj) {
            const int m = mt * 16 + kg * 4 + jj;
            lout[m * MOD + o * D + mch] = accs[q][jj];
        }
    }
    __syncthreads();

    // coalesced row-contiguous stores: flat idx -> (row, float4-chunk)
    for (int idx = t; idx < RTILE * F4R; idx += 256) {
        const int rr = idx / F4R, c = idx - rr * F4R;
        if (rr < nrows) {
            float4 v = *(const float4*)&lout[rr * MOD + c * 4];
            *(float4*)&out[(size_t)rid_s[rr] * OUT_SIZE + YOFF + c * 4] = v;
        }
    }
    __syncthreads();                         // before next seg reuses LDS
}

__global__ __launch_bounds__(256) void gemm_kernel(
    const float* __restrict__ x, const unsigned short* __restrict__ wt,
    const int* __restrict__ rowids, const int* __restrict__ offsets,
    const int* __restrict__ tileoff, const int* __restrict__ blk2e,
    float* __restrict__ out) {
    // union LDS: seg0 96*104 + 32*104 = 13312 halves (26.6 KB) is the max;
    // f32 out-tile reuse needs max 32*192*4 = 24.6 KB <= 26.6 KB.
    __shared__ __align__(16) unsigned short lds[13312];
    __shared__ int rid_s[RTILE];

    const int t   = threadIdx.x;
    const int seg = blockIdx.x / MAXTILES;
    const int tb  = blockIdx.x - seg * MAXTILES;
    const int e   = blk2e[tb];
    if (e < 0) return;
    const int tile  = tb - tileoff[e];
    const int r0    = offsets[e];
    const int cnt   = offsets[e + 1] - r0;
    const int rbase = r0 + tile * RTILE;
    const int nrows = min(RTILE, cnt - tile * RTILE);
    if (t < RTILE) rid_s[t] = rowids[rbase + min(t, nrows - 1)];  // clamp: ghosts gather real rows
    __syncthreads();

    const unsigned short* wt_e = wt + (size_t)e * WT_ELEM;
    if (seg == 0)
        do_seg<96, 96, 1,   0,   0,     0>(x, wt_e, rid_s, nrows, out, lds, lds + 9984, t);
    else if (seg == 1)
        do_seg<64, 64, 3,  96,  96,  9984>(x, wt_e, rid_s, nrows, out, lds, lds + 4608, t);
    else
        do_seg<32, 32, 5, 288, 288, 14592>(x, wt_e, rid_s, nrows, out, lds, lds + 1280, t);
}

// ---------------- launcher ----------------

extern "C" void kernel_launch(void* const* d_in, const int* in_sizes, int n_in,
                              void* d_out, int out_size, void* d_ws, size_t ws_size,
                              hipStream_t stream) {
    const float* weights = (const float*)d_in[0];   // [64, 14336] f32
    const float* x       = (const float*)d_in[1];   // [16384, 448] f32
    const int*   widx    = (const int*)d_in[2];     // [16384] int32
    float*       out     = (float*)d_out;           // [16384, 448] f32

    char* ws = (char*)d_ws;
    int* hists   = (int*)(ws + 0);                  // 64*64 ints = 16 KB
    int* offsets = (int*)(ws + 16384);              // 65
    int* tileoff = (int*)(ws + 16896);              // 65
    int* blk2e   = (int*)(ws + 17408);              // 576
    int* rowids  = (int*)(ws + 20480);              // 16384 ints
    unsigned short* wt = (unsigned short*)(ws + 86016);   // 64*15872 halves = 1.94 MB

    combo1_kernel <<<128, 256, 0, stream>>>(widx, weights, hists, wt);
    scatter_kernel<<<64,  256, 0, stream>>>(widx, hists, offsets, tileoff, blk2e, rowids);
    gemm_kernel   <<<3 * MAXTILES, 256, 0, stream>>>(x, wt, rowids, offsets, tileoff, blk2e, out);
    // duplicate launch: idempotent re-run to measure gemm cost via dur delta
    gemm_kernel   <<<3 * MAXTILES, 256, 0, stream>>>(x, wt, rowids, offsets, tileoff, blk2e, out);
}

// Round 14
// 32.037 us; speedup vs baseline: 1.6686x; 1.6686x over previous
//
#include <hip/hip_runtime.h>

// Indexed segmented linear, bucketed-by-element grouped GEMM with bf16 MFMA.
//   segments (mi, mo, d): (96,96,1), (64,64,3), (32,32,5)
//   y[b, o*d+m] = sum_i x[b, i*d+m] * W[idx[b], i*mo+o]
//
// Pipeline (3 kernels, no memset) — R12 with vectorized, widened prep:
//   K1 combo (256x256): blk 0-191 -> wprep, one block per (element, segment):
//        float4 reads -> ushort4 LDS writes -> packed 16B global stores of
//        Wt[e][seg][o][i] (padded rows, pads zeroed).
//        blk 192-255 -> per-256-row-chunk histogram of widx.
//   K2 scatter (64x256): fused scan -> rowids + offsets/tileoff/blk2e
//   K3 gemm (3*576x256): one block = (segment, 32-row tile). float4 gather
//        clause + packed de-interleave LDS writes; MFMA; transpose epilogue;
//        row-contiguous float4 stores. (R12 core, single launch.)

#define BATCH     16384
#define IN_SIZE   448
#define OUT_SIZE  448
#define W_SIZE    14336
#define NELEM     64
#define RTILE     32
#define MAXTILES  576         // >= 512 + 63 worst case
#define WT_ELEM   15872       // halves: 96*104 + 64*72 + 32*40

typedef __attribute__((ext_vector_type(8))) short short8;
typedef __attribute__((ext_vector_type(8))) unsigned short us8;
typedef __attribute__((ext_vector_type(4))) float f32x4;

__device__ __forceinline__ unsigned short f2bf(float f) {
    unsigned int u = __float_as_uint(f);
    u += 0x7fffu + ((u >> 16) & 1u);        // round-to-nearest-even
    return (unsigned short)(u >> 16);
}

// ---------------- K1: wprep (blk 0-191, one per (e,seg)) + hist (192-255) ----

template <int MI, int MO, int SRC, int DB>
__device__ __forceinline__ void wprep_seg(const float* __restrict__ we,
                                          unsigned short* __restrict__ de,
                                          unsigned short* lw, int t) {
    constexpr int LP  = MO + 4;              // LDS row stride (halves), %4==0
    constexpr int STR = MI + 8;              // out row stride (halves), %8==0
    constexpr int CNT = MI * MO;
    constexpr int C8  = STR / 8;             // 16B chunks per out row

    // read: float4 loads (coalesced), ushort4 LDS writes (same row, o%4==0)
    for (int g = t * 4; g < CNT; g += 1024) {
        const int i = g / MO, o = g - i * MO;
        const float4 v = *(const float4*)(we + SRC + g);
        ushort4 w = { f2bf(v.x), f2bf(v.y), f2bf(v.z), f2bf(v.w) };
        *(ushort4*)&lw[i * LP + o] = w;
    }
    __syncthreads();

    // write: gather 8 i's from LDS, one 16B global store per chunk
    for (int c = t; c < MO * C8; c += 256) {
        const int o = c / C8, i0 = (c - o * C8) * 8;
        us8 w;
        #pragma unroll
        for (int k = 0; k < 8; ++k)
            w[k] = (i0 + k < MI) ? lw[(i0 + k) * LP + o] : (unsigned short)0;
        *(us8*)&de[DB + o * STR + i0] = w;
    }
}

__global__ __launch_bounds__(256) void combo_kernel(
    const int* __restrict__ widx, const float* __restrict__ weights,
    int* __restrict__ hists, unsigned short* __restrict__ wt) {
    __shared__ __align__(16) unsigned short lw[9600];   // max 96*100
    __shared__ int h[NELEM];
    const int t = threadIdx.x;

    if (blockIdx.x < 192) {                  // ---- wprep: (e, seg) ----
        const int e = blockIdx.x / 3, seg = blockIdx.x - 3 * (blockIdx.x / 3);
        const float* __restrict__ we = weights + (size_t)e * W_SIZE;
        unsigned short* __restrict__ de = wt + (size_t)e * WT_ELEM;
        if (seg == 0)      wprep_seg<96, 96,     0,     0>(we, de, lw, t);
        else if (seg == 1) wprep_seg<64, 64,  9216,  9984>(we, de, lw, t);
        else               wprep_seg<32, 32, 13312, 14592>(we, de, lw, t);
        return;
    }
    // ---- hist ----
    const int b = blockIdx.x - 192;
    if (t < NELEM) h[t] = 0;
    __syncthreads();
    atomicAdd(&h[widx[b * 256 + t]], 1);
    __syncthreads();
    if (t < NELEM) hists[b * NELEM + t] = h[t];
}

// ---------------- K2: fused scan + scatter (rowids + tables) ----------------

__global__ __launch_bounds__(256) void scatter_kernel(
    const int* __restrict__ widx, const int* __restrict__ hists,
    int* __restrict__ offsets, int* __restrict__ tileoff, int* __restrict__ blk2e,
    int* __restrict__ rowids) {
    __shared__ int tot_s[NELEM], pre_s[NELEM], base_s[NELEM];
    __shared__ int off_s[NELEM + 1], tl_s[NELEM + 1];
    const int b = blockIdx.x, t = threadIdx.x;

    if (t < NELEM) {
        int before = 0, tot = 0;
        for (int c = 0; c < 64; ++c) {
            const int h = hists[c * NELEM + t];
            before += (c < b) ? h : 0;
            tot += h;
        }
        tot_s[t] = tot; pre_s[t] = before;
    }
    __syncthreads();
    if (t == 0) {
        int o = 0, tl = 0;
        for (int e = 0; e < NELEM; ++e) {
            off_s[e] = o; tl_s[e] = tl;
            o += tot_s[e]; tl += (tot_s[e] + RTILE - 1) >> 5;
        }
        off_s[NELEM] = o; tl_s[NELEM] = tl;
    }
    __syncthreads();
    if (t < NELEM) base_s[t] = off_s[t] + pre_s[t];

    if (b == 0) {
        if (t < NELEM) { offsets[t] = off_s[t]; tileoff[t] = tl_s[t]; }
        if (t == 0)    { offsets[NELEM] = off_s[NELEM]; tileoff[NELEM] = tl_s[NELEM]; }
        for (int i = t; i < MAXTILES; i += 256) blk2e[i] = -1;
        __syncthreads();
        if (t < NELEM)
            for (int bb = tl_s[t]; bb < tl_s[t + 1]; ++bb) blk2e[bb] = t;
    }
    __syncthreads();

    const int row = b * 256 + t;
    const int e = widx[row];
    const int pos = atomicAdd(&base_s[e], 1);
    rowids[pos] = row;
}

// ---------------- K3: grouped GEMM: packed staging + transpose epilogue ------

template <int MI, int MO, int D, int XOFF, int YOFF, int WB>
__device__ __forceinline__ void do_seg(const float* __restrict__ x,
                                       const unsigned short* __restrict__ wt_e,
                                       const int* rid_s, int nrows,
                                       float* __restrict__ out,
                                       unsigned short* lds_w, unsigned short* lds_x,
                                       int t) {
    constexpr int XP   = MI * D + 8;         // x row stride (halves)
    constexpr int WSTR = MI + 8;             // W row stride (halves)
    constexpr int NT   = MO / 16;
    constexpr int KB   = MI / 32;
    constexpr int MTL  = 2 * D;
    constexpr int WCH  = (MO * WSTR) / 8;    // 16B chunks of W seg
    constexpr int FPT  = (MI * D) / 8;       // floats per thread (8 thr/row)
    constexpr int NQ   = FPT / 4;            // float4 loads per thread
    constexpr int MOD  = MO * D;             // out floats per row in this seg
    constexpr int NTW  = (MTL * NT) / 4;     // C-tiles per wave (3/6/5)
    constexpr int F4R  = MOD / 4;            // float4 per out row (24/48/40)

    const int r = t >> 3, j = t & 7;         // 8 threads per row

    // issue all gather loads first (register clause; overlaps W staging)
    const float4* __restrict__ src =
        (const float4*)(x + (size_t)rid_s[r] * IN_SIZE + XOFF + j * FPT);
    float vv[FPT];
    #pragma unroll
    for (int q = 0; q < NQ; ++q) {
        const float4 v = src[q];
        vv[q * 4 + 0] = v.x; vv[q * 4 + 1] = v.y;
        vv[q * 4 + 2] = v.z; vv[q * 4 + 3] = v.w;
    }

    // stage W segment (bf16, pre-transposed, padded): linear uint4 copies (L2)
    const uint4* __restrict__ wsrc = (const uint4*)(wt_e + WB);
    for (int idx = t; idx < WCH; idx += 256) ((uint4*)lds_w)[idx] = wsrc[idx];

    // packed de-interleave writes (compile-time folded addresses)
    if (D == 1) {
        #pragma unroll
        for (int q = 0; q < NQ; ++q) {
            ushort4 w = { f2bf(vv[q * 4 + 0]), f2bf(vv[q * 4 + 1]),
                          f2bf(vv[q * 4 + 2]), f2bf(vv[q * 4 + 3]) };
            *(ushort4*)&lds_x[r * XP + j * FPT + q * 4] = w;
        }
    } else if (D == 3) {
        #pragma unroll
        for (int m = 0; m < 3; ++m) {        // i = j*8 + b, src lc = 3b + m
            us8 w;
            #pragma unroll
            for (int bq = 0; bq < 8; ++bq) w[bq] = f2bf(vv[3 * bq + m]);
            *(us8*)&lds_x[r * XP + m * MI + j * 8] = w;
        }
    } else {                                 // D == 5: i = j*4 + b, lc = 5b + m
        #pragma unroll
        for (int m = 0; m < 5; ++m) {
            ushort4 w = { f2bf(vv[m]), f2bf(vv[5 + m]),
                          f2bf(vv[10 + m]), f2bf(vv[15 + m]) };
            *(ushort4*)&lds_x[r * XP + m * MI + j * 4] = w;
        }
    }
    __syncthreads();

    // compute: C-tiles round-robin over 4 waves, results kept in registers
    const int lane = t & 63, w = t >> 6;
    const int row_l = lane & 15, kg = lane >> 4;
    f32x4 accs[NTW];
    #pragma unroll
    for (int q = 0; q < NTW; ++q) {
        const int ct = w + q * 4;
        const int mIdx = ct / NT, nt = ct - mIdx * NT;
        const int mt = mIdx & 1, mch = mIdx >> 1;
        f32x4 acc = {0.f, 0.f, 0.f, 0.f};
        #pragma unroll
        for (int kb = 0; kb < KB; ++kb) {
            const short8 a = *(const short8*)&lds_x[(mt * 16 + row_l) * XP + mch * MI + kb * 32 + kg * 8];
            const short8 b = *(const short8*)&lds_w[(nt * 16 + row_l) * WSTR + kb * 32 + kg * 8];
            acc = __builtin_amdgcn_mfma_f32_16x16x32_bf16(a, b, acc, 0, 0, 0);
        }
        accs[q] = acc;
    }
    __syncthreads();                         // all waves done reading lds_x/lds_w

    // transpose epilogue: acc -> LDS (f32 image of the 32xMOD out tile)
    float* __restrict__ lout = (float*)lds_w;        // lds_w is the LDS base
    #pragma unroll
    for (int q = 0; q < NTW; ++q) {
        const int ct = w + q * 4;
        const int mIdx = ct / NT, nt = ct - mIdx * NT;
        const int mt = mIdx & 1, mch = mIdx >> 1;
        const int o = nt * 16 + row_l;
        #pragma unroll
        for (int jj = 0; jj < 4; ++jj) {
            const int m = mt * 16 + kg * 4 + jj;
            lout[m * MOD + o * D + mch] = accs[q][jj];
        }
    }
    __syncthreads();

    // coalesced row-contiguous stores: flat idx -> (row, float4-chunk)
    for (int idx = t; idx < RTILE * F4R; idx += 256) {
        const int rr = idx / F4R, c = idx - rr * F4R;
        if (rr < nrows) {
            float4 v = *(const float4*)&lout[rr * MOD + c * 4];
            *(float4*)&out[(size_t)rid_s[rr] * OUT_SIZE + YOFF + c * 4] = v;
        }
    }
    __syncthreads();                         // before next seg reuses LDS
}

__global__ __launch_bounds__(256) void gemm_kernel(
    const float* __restrict__ x, const unsigned short* __restrict__ wt,
    const int* __restrict__ rowids, const int* __restrict__ offsets,
    const int* __restrict__ tileoff, const int* __restrict__ blk2e,
    float* __restrict__ out) {
    // union LDS: seg0 96*104 + 32*104 = 13312 halves (26.6 KB) is the max;
    // f32 out-tile reuse needs max 32*192*4 = 24.6 KB <= 26.6 KB.
    __shared__ __align__(16) unsigned short lds[13312];
    __shared__ int rid_s[RTILE];

    const int t   = threadIdx.x;
    const int seg = blockIdx.x / MAXTILES;
    const int tb  = blockIdx.x - seg * MAXTILES;
    const int e   = blk2e[tb];
    if (e < 0) return;
    const int tile  = tb - tileoff[e];
    const int r0    = offsets[e];
    const int cnt   = offsets[e + 1] - r0;
    const int rbase = r0 + tile * RTILE;
    const int nrows = min(RTILE, cnt - tile * RTILE);
    if (t < RTILE) rid_s[t] = rowids[rbase + min(t, nrows - 1)];  // clamp: ghosts gather real rows
    __syncthreads();

    const unsigned short* wt_e = wt + (size_t)e * WT_ELEM;
    if (seg == 0)
        do_seg<96, 96, 1,   0,   0,     0>(x, wt_e, rid_s, nrows, out, lds, lds + 9984, t);
    else if (seg == 1)
        do_seg<64, 64, 3,  96,  96,  9984>(x, wt_e, rid_s, nrows, out, lds, lds + 4608, t);
    else
        do_seg<32, 32, 5, 288, 288, 14592>(x, wt_e, rid_s, nrows, out, lds, lds + 1280, t);
}

// ---------------- launcher ----------------

extern "C" void kernel_launch(void* const* d_in, const int* in_sizes, int n_in,
                              void* d_out, int out_size, void* d_ws, size_t ws_size,
                              hipStream_t stream) {
    const float* weights = (const float*)d_in[0];   // [64, 14336] f32
    const float* x       = (const float*)d_in[1];   // [16384, 448] f32
    const int*   widx    = (const int*)d_in[2];     // [16384] int32
    float*       out     = (float*)d_out;           // [16384, 448] f32

    char* ws = (char*)d_ws;
    int* hists   = (int*)(ws + 0);                  // 64*64 ints = 16 KB
    int* offsets = (int*)(ws + 16384);              // 65
    int* tileoff = (int*)(ws + 16896);              // 65
    int* blk2e   = (int*)(ws + 17408);              // 576
    int* rowids  = (int*)(ws + 20480);              // 16384 ints
    unsigned short* wt = (unsigned short*)(ws + 86016);   // 64*15872 halves = 1.94 MB

    combo_kernel  <<<256, 256, 0, stream>>>(widx, weights, hists, wt);
    scatter_kernel<<<64,  256, 0, stream>>>(widx, hists, offsets, tileoff, blk2e, rowids);
    gemm_kernel   <<<3 * MAXTILES, 256, 0, stream>>>(x, wt, rowids, offsets, tileoff, blk2e, out);
}

// Round 15
// 31.479 us; speedup vs baseline: 1.6982x; 1.0177x over previous
//
#include <hip/hip_runtime.h>

// Indexed segmented linear, bucketed-by-element grouped GEMM with bf16 MFMA.
//   segments (mi, mo, d): (96,96,1), (64,64,3), (32,32,5)
//   y[b, o*d+m] = sum_i x[b, i*d+m] * W[idx[b], i*mo+o]
//
// Pipeline (2 kernels, no memset):
//   K1 combo (193x256): blk 0-191 -> wprep, one block per (element, segment):
//        float4 reads -> ushort4 LDS writes -> packed 16B stores of
//        Wt[e][seg][o][i] (padded rows). blk 192 -> table block: LDS histogram
//        of widx, serial scan, writes offsets/tileoff/blk2e.
//   K2 gemm (3*576x256): one block = (segment, 32-row tile). Derives its own
//        row list from widx via bitmask rank-scan (deterministic, no scatter
//        kernel): per-thread 64-bit match mask over (t,i) order, shfl prefix,
//        emit ranks [tile*32, tile*32+32). Then float4 gather clause + packed
//        de-interleave LDS staging; MFMA; transpose epilogue; row-contiguous
//        float4 stores. (R14 core otherwise.)

#define BATCH     16384
#define IN_SIZE   448
#define OUT_SIZE  448
#define W_SIZE    14336
#define NELEM     64
#define RTILE     32
#define MAXTILES  576         // >= 512 + 63 worst case
#define WT_ELEM   15872       // halves: 96*104 + 64*72 + 32*40

typedef __attribute__((ext_vector_type(8))) short short8;
typedef __attribute__((ext_vector_type(8))) unsigned short us8;
typedef __attribute__((ext_vector_type(4))) float f32x4;

__device__ __forceinline__ unsigned short f2bf(float f) {
    unsigned int u = __float_as_uint(f);
    u += 0x7fffu + ((u >> 16) & 1u);        // round-to-nearest-even
    return (unsigned short)(u >> 16);
}

// ---------------- K1: wprep (blk 0-191) + table block (blk 192) ----------------

template <int MI, int MO, int SRC, int DB>
__device__ __forceinline__ void wprep_seg(const float* __restrict__ we,
                                          unsigned short* __restrict__ de,
                                          unsigned short* lw, int t) {
    constexpr int LP  = MO + 4;              // LDS row stride (halves), %4==0
    constexpr int STR = MI + 8;              // out row stride (halves), %8==0
    constexpr int CNT = MI * MO;
    constexpr int C8  = STR / 8;             // 16B chunks per out row

    for (int g = t * 4; g < CNT; g += 1024) {
        const int i = g / MO, o = g - i * MO;
        const float4 v = *(const float4*)(we + SRC + g);
        ushort4 w = { f2bf(v.x), f2bf(v.y), f2bf(v.z), f2bf(v.w) };
        *(ushort4*)&lw[i * LP + o] = w;
    }
    __syncthreads();

    for (int c = t; c < MO * C8; c += 256) {
        const int o = c / C8, i0 = (c - o * C8) * 8;
        us8 w;
        #pragma unroll
        for (int k = 0; k < 8; ++k)
            w[k] = (i0 + k < MI) ? lw[(i0 + k) * LP + o] : (unsigned short)0;
        *(us8*)&de[DB + o * STR + i0] = w;
    }
}

__global__ __launch_bounds__(256) void combo_kernel(
    const int* __restrict__ widx, const float* __restrict__ weights,
    int* __restrict__ offsets, int* __restrict__ tileoff, int* __restrict__ blk2e,
    unsigned short* __restrict__ wt) {
    __shared__ __align__(16) unsigned short lw[9600];   // max 96*100
    const int t = threadIdx.x;

    if (blockIdx.x < 192) {                  // ---- wprep: (e, seg) ----
        const int e = blockIdx.x / 3, seg = blockIdx.x - 3 * (blockIdx.x / 3);
        const float* __restrict__ we = weights + (size_t)e * W_SIZE;
        unsigned short* __restrict__ de = wt + (size_t)e * WT_ELEM;
        if (seg == 0)      wprep_seg<96, 96,     0,     0>(we, de, lw, t);
        else if (seg == 1) wprep_seg<64, 64,  9216,  9984>(we, de, lw, t);
        else               wprep_seg<32, 32, 13312, 14592>(we, de, lw, t);
        return;
    }

    // ---- table block: histogram + scan + tables ----
    __shared__ int h[NELEM];
    __shared__ int off_s[NELEM + 1], tl_s[NELEM + 1];
    if (t < NELEM) h[t] = 0;
    __syncthreads();
    for (int i = 0; i < 64; ++i)
        atomicAdd(&h[widx[i * 256 + t]], 1);
    __syncthreads();
    if (t == 0) {
        int o = 0, tl = 0;
        for (int e = 0; e < NELEM; ++e) {
            off_s[e] = o; tl_s[e] = tl;
            o += h[e]; tl += (h[e] + RTILE - 1) >> 5;
        }
        off_s[NELEM] = o; tl_s[NELEM] = tl;
    }
    __syncthreads();
    if (t <= NELEM) { offsets[t] = off_s[t]; tileoff[t] = tl_s[t]; }
    for (int i = t; i < MAXTILES; i += 256) blk2e[i] = -1;
    __syncthreads();
    if (t < NELEM)
        for (int bb = tl_s[t]; bb < tl_s[t + 1]; ++bb) blk2e[bb] = t;
}

// ---------------- K2: grouped GEMM with in-block rank-scan ----------------

template <int MI, int MO, int D, int XOFF, int YOFF, int WB>
__device__ __forceinline__ void do_seg(const float* __restrict__ x,
                                       const unsigned short* __restrict__ wt_e,
                                       const int* rid_s, int nrows,
                                       float* __restrict__ out,
                                       unsigned short* lds_w, unsigned short* lds_x,
                                       int t) {
    constexpr int XP   = MI * D + 8;         // x row stride (halves)
    constexpr int WSTR = MI + 8;             // W row stride (halves)
    constexpr int NT   = MO / 16;
    constexpr int KB   = MI / 32;
    constexpr int MTL  = 2 * D;
    constexpr int WCH  = (MO * WSTR) / 8;    // 16B chunks of W seg
    constexpr int FPT  = (MI * D) / 8;       // floats per thread (8 thr/row)
    constexpr int NQ   = FPT / 4;            // float4 loads per thread
    constexpr int MOD  = MO * D;             // out floats per row in this seg
    constexpr int NTW  = (MTL * NT) / 4;     // C-tiles per wave (3/6/5)
    constexpr int F4R  = MOD / 4;            // float4 per out row (24/48/40)

    const int r = t >> 3, j = t & 7;         // 8 threads per row

    // issue all gather loads first (register clause; overlaps W staging)
    const float4* __restrict__ src =
        (const float4*)(x + (size_t)rid_s[r] * IN_SIZE + XOFF + j * FPT);
    float vv[FPT];
    #pragma unroll
    for (int q = 0; q < NQ; ++q) {
        const float4 v = src[q];
        vv[q * 4 + 0] = v.x; vv[q * 4 + 1] = v.y;
        vv[q * 4 + 2] = v.z; vv[q * 4 + 3] = v.w;
    }

    // stage W segment (bf16, pre-transposed, padded): linear uint4 copies (L2)
    const uint4* __restrict__ wsrc = (const uint4*)(wt_e + WB);
    for (int idx = t; idx < WCH; idx += 256) ((uint4*)lds_w)[idx] = wsrc[idx];

    // packed de-interleave writes (compile-time folded addresses)
    if (D == 1) {
        #pragma unroll
        for (int q = 0; q < NQ; ++q) {
            ushort4 w = { f2bf(vv[q * 4 + 0]), f2bf(vv[q * 4 + 1]),
                          f2bf(vv[q * 4 + 2]), f2bf(vv[q * 4 + 3]) };
            *(ushort4*)&lds_x[r * XP + j * FPT + q * 4] = w;
        }
    } else if (D == 3) {
        #pragma unroll
        for (int m = 0; m < 3; ++m) {        // i = j*8 + b, src lc = 3b + m
            us8 w;
            #pragma unroll
            for (int bq = 0; bq < 8; ++bq) w[bq] = f2bf(vv[3 * bq + m]);
            *(us8*)&lds_x[r * XP + m * MI + j * 8] = w;
        }
    } else {                                 // D == 5: i = j*4 + b, lc = 5b + m
        #pragma unroll
        for (int m = 0; m < 5; ++m) {
            ushort4 w = { f2bf(vv[m]), f2bf(vv[5 + m]),
                          f2bf(vv[10 + m]), f2bf(vv[15 + m]) };
            *(ushort4*)&lds_x[r * XP + m * MI + j * 4] = w;
        }
    }
    __syncthreads();

    // compute: C-tiles round-robin over 4 waves, results kept in registers
    const int lane = t & 63, w = t >> 6;
    const int row_l = lane & 15, kg = lane >> 4;
    f32x4 accs[NTW];
    #pragma unroll
    for (int q = 0; q < NTW; ++q) {
        const int ct = w + q * 4;
        const int mIdx = ct / NT, nt = ct - mIdx * NT;
        const int mt = mIdx & 1, mch = mIdx >> 1;
        f32x4 acc = {0.f, 0.f, 0.f, 0.f};
        #pragma unroll
        for (int kb = 0; kb < KB; ++kb) {
            const short8 a = *(const short8*)&lds_x[(mt * 16 + row_l) * XP + mch * MI + kb * 32 + kg * 8];
            const short8 b = *(const short8*)&lds_w[(nt * 16 + row_l) * WSTR + kb * 32 + kg * 8];
            acc = __builtin_amdgcn_mfma_f32_16x16x32_bf16(a, b, acc, 0, 0, 0);
        }
        accs[q] = acc;
    }
    __syncthreads();                         // all waves done reading lds_x/lds_w

    // transpose epilogue: acc -> LDS (f32 image of the 32xMOD out tile)
    float* __restrict__ lout = (float*)lds_w;        // lds_w is the LDS base
    #pragma unroll
    for (int q = 0; q < NTW; ++q) {
        const int ct = w + q * 4;
        const int mIdx = ct / NT, nt = ct - mIdx * NT;
        const int mt = mIdx & 1, mch = mIdx >> 1;
        const int o = nt * 16 + row_l;
        #pragma unroll
        for (int jj = 0; jj < 4; ++jj) {
            const int m = mt * 16 + kg * 4 + jj;
            lout[m * MOD + o * D + mch] = accs[q][jj];
        }
    }
    __syncthreads();

    // coalesced row-contiguous stores: flat idx -> (row, float4-chunk)
    for (int idx = t; idx < RTILE * F4R; idx += 256) {
        const int rr = idx / F4R, c = idx - rr * F4R;
        if (rr < nrows) {
            float4 v = *(const float4*)&lout[rr * MOD + c * 4];
            *(float4*)&out[(size_t)rid_s[rr] * OUT_SIZE + YOFF + c * 4] = v;
        }
    }
}

__global__ __launch_bounds__(256) void gemm_kernel(
    const float* __restrict__ x, const unsigned short* __restrict__ wt,
    const int* __restrict__ widx, const int* __restrict__ offsets,
    const int* __restrict__ tileoff, const int* __restrict__ blk2e,
    float* __restrict__ out) {
    // union LDS: seg0 96*104 + 32*104 = 13312 halves (26.6 KB) is the max;
    // f32 out-tile reuse needs max 32*192*4 = 24.6 KB <= 26.6 KB.
    __shared__ __align__(16) unsigned short lds[13312];
    __shared__ int rid_s[RTILE];
    __shared__ int wsum[4];

    const int t   = threadIdx.x;
    const int seg = blockIdx.x / MAXTILES;
    const int tb  = blockIdx.x - seg * MAXTILES;
    const int e   = blk2e[tb];
    if (e < 0) return;
    const int tile  = tb - tileoff[e];
    const int cnt   = offsets[e + 1] - offsets[e];
    const int lo    = tile * RTILE;
    const int nrows = min(RTILE, cnt - lo);

    // ---- rank-scan: derive rid_s from widx (deterministic, no atomics) ----
    // order: rank over (t, i) lexicographic; row r = i*256 + t.
    {
        unsigned long long m = 0;
        #pragma unroll
        for (int i = 0; i < 64; ++i)
            m |= (unsigned long long)(widx[i * 256 + t] == e) << i;
        const int c = __popcll(m);
        // wave-inclusive scan of c
        int xacc = c;
        #pragma unroll
        for (int d = 1; d < 64; d <<= 1) {
            const int v = __shfl_up(xacc, d, 64);
            if ((t & 63) >= d) xacc += v;
        }
        if ((t & 63) == 63) wsum[t >> 6] = xacc;
        __syncthreads();
        int wbase = 0;
        #pragma unroll
        for (int wv = 0; wv < 4; ++wv) wbase += (wv < (t >> 6)) ? wsum[wv] : 0;
        const int p = wbase + xacc - c;      // exclusive prefix over all threads
        if (p < lo + RTILE && p + c > lo) {
            unsigned long long mm = m;
            int k = p;
            while (mm) {
                const int i = __ffsll((long long)mm) - 1;
                if (k >= lo) rid_s[k - lo] = i * 256 + t;
                ++k;
                if (k >= lo + RTILE) break;
                mm &= mm - 1;
            }
        }
        __syncthreads();
        if (t >= nrows && t < RTILE) rid_s[t] = rid_s[0];   // ghosts -> valid row
        __syncthreads();
    }

    const unsigned short* wt_e = wt + (size_t)e * WT_ELEM;
    if (seg == 0)
        do_seg<96, 96, 1,   0,   0,     0>(x, wt_e, rid_s, nrows, out, lds, lds + 9984, t);
    else if (seg == 1)
        do_seg<64, 64, 3,  96,  96,  9984>(x, wt_e, rid_s, nrows, out, lds, lds + 4608, t);
    else
        do_seg<32, 32, 5, 288, 288, 14592>(x, wt_e, rid_s, nrows, out, lds, lds + 1280, t);
}

// ---------------- launcher ----------------

extern "C" void kernel_launch(void* const* d_in, const int* in_sizes, int n_in,
                              void* d_out, int out_size, void* d_ws, size_t ws_size,
                              hipStream_t stream) {
    const float* weights = (const float*)d_in[0];   // [64, 14336] f32
    const float* x       = (const float*)d_in[1];   // [16384, 448] f32
    const int*   widx    = (const int*)d_in[2];     // [16384] int32
    float*       out     = (float*)d_out;           // [16384, 448] f32

    char* ws = (char*)d_ws;
    int* offsets = (int*)(ws + 0);                  // 65
    int* tileoff = (int*)(ws + 512);                // 65
    int* blk2e   = (int*)(ws + 1024);               // 576
    unsigned short* wt = (unsigned short*)(ws + 8192);   // 64*15872 halves = 1.94 MB

    combo_kernel<<<193, 256, 0, stream>>>(widx, weights, offsets, tileoff, blk2e, wt);
    gemm_kernel <<<3 * MAXTILES, 256, 0, stream>>>(x, wt, widx, offsets,
                                                   tileoff, blk2e, out);
}